// Round 11
// baseline (11050.726 us; speedup 1.0000x reference)
//
#include <hip/hip_runtime.h>

#define D 256
#define GSHIFT 4
#define GSIZE 16          // nodes per group (= nodes per agg_gemm block)
#define KMAX4 6400        // max groups (scatterB LDS hist: 25.6 KB)
#define NB_P 256          // partition blocks
#define TN 16             // nodes per agg_gemm block
#define CAPG 1024         // fixed region capacity per group (mean 512, ~22 sigma)

using bf16x8 = __attribute__((ext_vector_type(8))) short;
using f32x4  = __attribute__((ext_vector_type(4))) float;

__device__ inline float bf_lo(unsigned int u) {
    return __builtin_bit_cast(float, u << 16);
}
__device__ inline float bf_hi(unsigned int u) {
    return __builtin_bit_cast(float, u & 0xffff0000u);
}
__device__ inline unsigned short f2bf(float f) {
    unsigned int x = __builtin_bit_cast(unsigned int, f);
    unsigned int r = (x + 0x7fffu + ((x >> 16) & 1u)) >> 16;   // RNE
    return (unsigned short)r;
}

// ---------------------------------------------------------------------------
// prep: conv_feature || conv_w || zero(gcnt), via blockIdx range split.
// No LDS -> full occupancy streaming.
// ---------------------------------------------------------------------------
__global__ __launch_bounds__(256) void prep_kernel(
    const float* __restrict__ feature, unsigned short* __restrict__ fbf, long n8,
    const float* __restrict__ W, unsigned short* __restrict__ Wt,
    int* __restrict__ gcnt, int K, int nConvF, int nConvW)
{
    const int b = blockIdx.x, t = threadIdx.x;

    if (b < nConvF) {
        long i = (long)b * 256 + t;
        if (i < n8) {
            const float4* p = reinterpret_cast<const float4*>(feature + i * 8);
            float4 v0 = p[0], v1 = p[1];
            uint4 r;
            r.x = (unsigned int)f2bf(v0.x) | ((unsigned int)f2bf(v0.y) << 16);
            r.y = (unsigned int)f2bf(v0.z) | ((unsigned int)f2bf(v0.w) << 16);
            r.z = (unsigned int)f2bf(v1.x) | ((unsigned int)f2bf(v1.y) << 16);
            r.w = (unsigned int)f2bf(v1.z) | ((unsigned int)f2bf(v1.w) << 16);
            *reinterpret_cast<uint4*>(fbf + i * 8) = r;
        }
        return;
    }
    if (b < nConvF + nConvW) {
        int i = (b - nConvF) * 256 + t;
        if (i < D * D / 4) {
            int n  = i >> 6;
            int k0 = (i & 63) * 4;
            float a  = W[(size_t)(k0 + 0) * D + n];
            float bb = W[(size_t)(k0 + 1) * D + n];
            float c  = W[(size_t)(k0 + 2) * D + n];
            float d  = W[(size_t)(k0 + 3) * D + n];
            uint2 r;
            r.x = (unsigned int)f2bf(a) | ((unsigned int)f2bf(bb) << 16);
            r.y = (unsigned int)f2bf(c) | ((unsigned int)f2bf(d) << 16);
            *reinterpret_cast<uint2*>(Wt + (size_t)n * D + k0) = r;
        }
        return;
    }
    // zero gcnt
    int i = (b - nConvF - nConvW) * 256 + t;
    if (i < K) gcnt[i] = 0;
}

// ---------------------------------------------------------------------------
// scatterB v3 (self-contained, fixed regions): per-block LDS hist over own
// chunk -> one global atomic claim per nonzero bin -> LDS-cursor scatter of
// packed (src<<4)|dstLocal into group region [k*CAPG, k*CAPG+CAPG).
// ---------------------------------------------------------------------------
__global__ __launch_bounds__(256) void scatterB_kernel(
    const int* __restrict__ src, const int* __restrict__ dst,
    int* __restrict__ gcnt, int* __restrict__ csrPacked,
    int E, int K, int chunk)
{
    __shared__ int h[KMAX4];     // counts, then absolute cursors
    const int b = blockIdx.x, t = threadIdx.x;
    for (int i = t; i < K; i += 256) h[i] = 0;
    __syncthreads();
    const int beg = b * chunk;
    const int end = min(beg + chunk, E);
    for (int i = beg + t; i < end; i += 256)
        atomicAdd(&h[dst[i] >> GSHIFT], 1);
    __syncthreads();
    for (int i = t; i < K; i += 256) {
        int c = h[i];
        h[i] = c ? atomicAdd(&gcnt[i], c) : 0;   // claim run; h = abs base in region
    }
    __syncthreads();
    for (int i = beg + t; i < end; i += 256) {
        int d = dst[i];
        int k = d >> GSHIFT;
        int r = atomicAdd(&h[k], 1);             // LDS atomic, absolute slot
        if (r < CAPG)
            csrPacked[(size_t)k * CAPG + r] = (src[i] << GSHIFT) | (d & (GSIZE - 1));
    }
}

// ---------------------------------------------------------------------------
// Fused in-LDS sort + aggregate + GEMM at 16-node granularity.
// Block b owns group b = nodes [16b,16b+16), edges csrPacked[b*CAPG .. +cnt).
// P0: counting sort of the group's packed edges into lsrc (LDS).
// P1: gather: 4 waves x 4 nodes; half-wave edge split (lanes 0-31 even edges,
//     32-63 odd), uint4 loads (8 bf16 cols/lane), fp32 acc, shfl_xor merge,
//     bf16 row -> LDS A[16][264].
// P2: GEMM 16x256 @ 256x256 MFMA; wave w owns col-tiles [4w,4w+4);
//     + bias + ReLU -> out (fp32).
// LDS ~12.7 KB -> wave-limited occupancy, gather concurrency preserved.
// ---------------------------------------------------------------------------
__global__ __launch_bounds__(256) void agg_gemm_kernel(
    const unsigned short* __restrict__ fbf,
    const int* __restrict__ csrPacked,
    const int* __restrict__ gcnt,
    const unsigned short* __restrict__ Wt,
    const float* __restrict__ bias,
    float* __restrict__ out, int N)
{
    __shared__ int lsrc[CAPG];
    __shared__ int nBeg[TN], nCnt[TN], nCur[TN];
    __shared__ unsigned short A[TN][D + 8];    // 8448 B, +8 pad

    const int blk  = blockIdx.x;
    const int t    = threadIdx.x;
    const int wave = t >> 6;
    const int lane = t & 63;
    const int sub  = lane & 31;
    const int half = lane >> 5;
    const int node0 = blk * TN;
    const size_t colOff = (size_t)(sub << 3);

    const size_t beg = (size_t)blk * CAPG;
    const int cnt = min(gcnt[blk], CAPG);

    // ---- P0: counting sort into lsrc grouped by local node ----
    if (t < TN) nCnt[t] = 0;
    __syncthreads();
    for (int i = t; i < cnt; i += 256)
        atomicAdd(&nCnt[csrPacked[beg + i] & (GSIZE - 1)], 1);
    __syncthreads();
    if (t == 0) {
        int run = 0;
        for (int j = 0; j < TN; ++j) { nBeg[j] = run; run += nCnt[j]; }
    }
    __syncthreads();
    if (t < TN) nCur[t] = nBeg[t];
    __syncthreads();
    for (int i = t; i < cnt; i += 256) {
        int p = csrPacked[beg + i];
        int r = atomicAdd(&nCur[p & (GSIZE - 1)], 1);
        lsrc[r] = p >> GSHIFT;
    }
    __syncthreads();

    // ---- P1: gather 4 nodes per wave ----
    for (int ni = 0; ni < 4; ++ni) {
        const int l = (wave << 2) + ni;
        const int node = node0 + l;
        float a0 = 0.f, a1 = 0.f, a2 = 0.f, a3 = 0.f;
        float a4 = 0.f, a5 = 0.f, a6 = 0.f, a7 = 0.f;
        if (node < N) {
            const int b0 = nBeg[l];
            const int c0 = nCnt[l];
            int j = 0;
            for (; j + 3 < c0; j += 4) {
                int s0 = lsrc[b0 + j + half];
                int s1 = lsrc[b0 + j + 2 + half];
                uint4 v0 = *reinterpret_cast<const uint4*>(fbf + ((size_t)s0 << 8) + colOff);
                uint4 v1 = *reinterpret_cast<const uint4*>(fbf + ((size_t)s1 << 8) + colOff);
                a0 += bf_lo(v0.x); a1 += bf_hi(v0.x); a2 += bf_lo(v0.y); a3 += bf_hi(v0.y);
                a4 += bf_lo(v0.z); a5 += bf_hi(v0.z); a6 += bf_lo(v0.w); a7 += bf_hi(v0.w);
                a0 += bf_lo(v1.x); a1 += bf_hi(v1.x); a2 += bf_lo(v1.y); a3 += bf_hi(v1.y);
                a4 += bf_lo(v1.z); a5 += bf_hi(v1.z); a6 += bf_lo(v1.w); a7 += bf_hi(v1.w);
            }
            if (j + 1 < c0) {
                int s0 = lsrc[b0 + j + half];
                uint4 v0 = *reinterpret_cast<const uint4*>(fbf + ((size_t)s0 << 8) + colOff);
                a0 += bf_lo(v0.x); a1 += bf_hi(v0.x); a2 += bf_lo(v0.y); a3 += bf_hi(v0.y);
                a4 += bf_lo(v0.z); a5 += bf_hi(v0.z); a6 += bf_lo(v0.w); a7 += bf_hi(v0.w);
                j += 2;
            }
            if (j < c0 && half == 0) {
                int s0 = lsrc[b0 + j];
                uint4 v0 = *reinterpret_cast<const uint4*>(fbf + ((size_t)s0 << 8) + colOff);
                a0 += bf_lo(v0.x); a1 += bf_hi(v0.x); a2 += bf_lo(v0.y); a3 += bf_hi(v0.y);
                a4 += bf_lo(v0.z); a5 += bf_hi(v0.z); a6 += bf_lo(v0.w); a7 += bf_hi(v0.w);
            }
        }
        a0 += __shfl_xor(a0, 32); a1 += __shfl_xor(a1, 32);
        a2 += __shfl_xor(a2, 32); a3 += __shfl_xor(a3, 32);
        a4 += __shfl_xor(a4, 32); a5 += __shfl_xor(a5, 32);
        a6 += __shfl_xor(a6, 32); a7 += __shfl_xor(a7, 32);
        if (half == 0) {
            uint4 r;
            r.x = (unsigned int)f2bf(a0) | ((unsigned int)f2bf(a1) << 16);
            r.y = (unsigned int)f2bf(a2) | ((unsigned int)f2bf(a3) << 16);
            r.z = (unsigned int)f2bf(a4) | ((unsigned int)f2bf(a5) << 16);
            r.w = (unsigned int)f2bf(a6) | ((unsigned int)f2bf(a7) << 16);
            *reinterpret_cast<uint4*>(&A[l][sub << 3]) = r;
        }
    }
    __syncthreads();

    // ---- P2: GEMM 16x256 ----
    const int lr = lane & 15;
    const int lg = lane >> 4;

    bf16x8 afr[8];
#pragma unroll
    for (int ks = 0; ks < 8; ++ks)
        afr[ks] = *reinterpret_cast<const bf16x8*>(&A[lr][ks * 32 + lg * 8]);

#pragma unroll
    for (int c = 0; c < 4; ++c) {
        const int ct = (wave << 2) + c;
        f32x4 acc = {0.f, 0.f, 0.f, 0.f};
        const unsigned short* bp = Wt + (size_t)(ct * 16 + lr) * D + lg * 8;
#pragma unroll
        for (int ks = 0; ks < 8; ++ks) {
            bf16x8 bfr = *reinterpret_cast<const bf16x8*>(bp + ks * 32);
            acc = __builtin_amdgcn_mfma_f32_16x16x32_bf16(afr[ks], bfr, acc, 0, 0, 0);
        }
        const float bv = bias[ct * 16 + lr];
#pragma unroll
        for (int jj = 0; jj < 4; ++jj) {
            int row = node0 + lg * 4 + jj;
            if (row < N) {
                float v = acc[jj] + bv;
                out[(size_t)row * D + ct * 16 + lr] = v > 0.f ? v : 0.f;
            }
        }
    }
}

// ---------------------------------------------------------------------------
// Fallback kernels (ws too small): direct atomic scatter + VALU linear.
// ---------------------------------------------------------------------------
__global__ __launch_bounds__(256) void scatter_kernel(
    const float* __restrict__ feature, const int* __restrict__ src,
    const int* __restrict__ dst, float* __restrict__ agg, int E)
{
    int edge = blockIdx.x * (blockDim.x >> 6) + (threadIdx.x >> 6);
    int lane = threadIdx.x & 63;
    if (edge >= E) return;
    int s = src[edge];
    int d = dst[edge];
    const float4 v = *reinterpret_cast<const float4*>(feature + (size_t)s * D + lane * 4);
    float* o = agg + (size_t)d * D + lane * 4;
    atomicAdd(o + 0, v.x);
    atomicAdd(o + 1, v.y);
    atomicAdd(o + 2, v.z);
    atomicAdd(o + 3, v.w);
}

#define BM 32
__global__ __launch_bounds__(256) void linear_relu_kernel(
    float* __restrict__ h, const float* __restrict__ W,
    const float* __restrict__ b, int n_nodes)
{
    __shared__ float sA[BM][D];
    const int node0 = blockIdx.x * BM;
    const int t = threadIdx.x;
    for (int m = 0; m < BM; ++m) {
        int nd = node0 + m;
        sA[m][t] = (nd < n_nodes) ? h[(size_t)nd * D + t] : 0.0f;
    }
    __syncthreads();
    float acc[BM];
#pragma unroll
    for (int m = 0; m < BM; ++m) acc[m] = 0.0f;
    for (int kk = 0; kk < D; ++kk) {
        float w = W[kk * D + t];
#pragma unroll
        for (int m = 0; m < BM; ++m) acc[m] += sA[m][kk] * w;
    }
    const float bias = b[t];
    for (int m = 0; m < BM; ++m) {
        int nd = node0 + m;
        if (nd < n_nodes) {
            float v = acc[m] + bias;
            h[(size_t)nd * D + t] = v > 0.0f ? v : 0.0f;
        }
    }
}

// ---------------------------------------------------------------------------
extern "C" void kernel_launch(void* const* d_in, const int* in_sizes, int n_in,
                              void* d_out, int out_size, void* d_ws, size_t ws_size,
                              hipStream_t stream)
{
    const float* feature = (const float*)d_in[0];
    const int*   src     = (const int*)d_in[1];
    const int*   dst     = (const int*)d_in[2];
    const float* W       = (const float*)d_in[3];
    const float* b       = (const float*)d_in[4];
    float*       out     = (float*)d_out;

    const int E = in_sizes[1];
    const int N = in_sizes[0] / D;
    const int K = (N + GSIZE - 1) >> GSHIFT;        // 16-node groups
    const int chunk = (E + NB_P - 1) / NB_P;

    // ---- workspace layout -------------------------------------------------
    size_t off = 0;
    auto alloc = [&](size_t bytes, size_t align) {
        off = (off + align - 1) / align * align;
        size_t r = off; off += bytes; return r;
    };
    size_t o_gcnt   = alloc((size_t)K * 4, 16);
    size_t o_packed = alloc((size_t)K * CAPG * 4, 16);
    size_t o_wt     = alloc((size_t)D * D * 2, 16);
    size_t o_fbf    = alloc((size_t)N * D * 2, 16);
    size_t need_full = off;

    char* ws = (char*)d_ws;

    // sanity: average edges/group must fit CAPG with wide margin
    const bool cap_ok = ((long)E / K) * 2 + 64 <= CAPG;

    if (ws_size >= need_full && K <= KMAX4 && cap_ok) {
        int* gcnt      = (int*)(ws + o_gcnt);
        int* csrPacked = (int*)(ws + o_packed);
        unsigned short* Wt  = (unsigned short*)(ws + o_wt);
        unsigned short* fbf = (unsigned short*)(ws + o_fbf);

        const long n8 = (long)N * D / 8;
        const int nConvF = (int)((n8 + 255) / 256);
        const int nConvW = (D * D / 4 + 255) / 256;
        const int nZero  = (K + 255) / 256;

        prep_kernel<<<nConvF + nConvW + nZero, 256, 0, stream>>>(
            feature, fbf, n8, W, Wt, gcnt, K, nConvF, nConvW);

        scatterB_kernel<<<NB_P, 256, 0, stream>>>(
            src, dst, gcnt, csrPacked, E, K, chunk);

        agg_gemm_kernel<<<(N + TN - 1) / TN, 256, 0, stream>>>(
            fbf, csrPacked, gcnt, Wt, b, out, N);
    } else {
        hipMemsetAsync(d_out, 0, (size_t)out_size * sizeof(float), stream);
        scatter_kernel<<<(E + 3) / 4, 256, 0, stream>>>(feature, src, dst, out, E);
        linear_relu_kernel<<<(N + BM - 1) / BM, 256, 0, stream>>>(out, W, b, N);
    }
}

// Round 12
// 408.713 us; speedup vs baseline: 27.0378x; 27.0378x over previous
//
#include <hip/hip_runtime.h>

#define D 256
#define GSHIFT 4
#define GSIZE 16          // nodes per group (= nodes per agg_gemm block)
#define KMAX4 6400        // max groups (scatterB LDS hist: 25.6 KB)
#define NB_P 256          // partition blocks
#define TN 16             // nodes per agg_gemm block
#define CAPG 2048         // fixed region capacity per group (mean 512, ~68 sigma)

using bf16x8 = __attribute__((ext_vector_type(8))) short;
using f32x4  = __attribute__((ext_vector_type(4))) float;

__device__ inline float bf_lo(unsigned int u) {
    return __builtin_bit_cast(float, u << 16);
}
__device__ inline float bf_hi(unsigned int u) {
    return __builtin_bit_cast(float, u & 0xffff0000u);
}
__device__ inline unsigned short f2bf(float f) {
    unsigned int x = __builtin_bit_cast(unsigned int, f);
    unsigned int r = (x + 0x7fffu + ((x >> 16) & 1u)) >> 16;   // RNE
    return (unsigned short)r;
}

// ---------------------------------------------------------------------------
// prep: conv_feature || conv_w || zero(gcnt), via blockIdx range split.
// No LDS -> full occupancy streaming.
// ---------------------------------------------------------------------------
__global__ __launch_bounds__(256) void prep_kernel(
    const float* __restrict__ feature, unsigned short* __restrict__ fbf, long n8,
    const float* __restrict__ W, unsigned short* __restrict__ Wt,
    int* __restrict__ gcnt, int K, int nConvF, int nConvW)
{
    const int b = blockIdx.x, t = threadIdx.x;

    if (b < nConvF) {
        long i = (long)b * 256 + t;
        if (i < n8) {
            const float4* p = reinterpret_cast<const float4*>(feature + i * 8);
            float4 v0 = p[0], v1 = p[1];
            uint4 r;
            r.x = (unsigned int)f2bf(v0.x) | ((unsigned int)f2bf(v0.y) << 16);
            r.y = (unsigned int)f2bf(v0.z) | ((unsigned int)f2bf(v0.w) << 16);
            r.z = (unsigned int)f2bf(v1.x) | ((unsigned int)f2bf(v1.y) << 16);
            r.w = (unsigned int)f2bf(v1.z) | ((unsigned int)f2bf(v1.w) << 16);
            *reinterpret_cast<uint4*>(fbf + i * 8) = r;
        }
        return;
    }
    if (b < nConvF + nConvW) {
        int i = (b - nConvF) * 256 + t;
        if (i < D * D / 4) {
            int n  = i >> 6;
            int k0 = (i & 63) * 4;
            float a  = W[(size_t)(k0 + 0) * D + n];
            float bb = W[(size_t)(k0 + 1) * D + n];
            float c  = W[(size_t)(k0 + 2) * D + n];
            float d  = W[(size_t)(k0 + 3) * D + n];
            uint2 r;
            r.x = (unsigned int)f2bf(a) | ((unsigned int)f2bf(bb) << 16);
            r.y = (unsigned int)f2bf(c) | ((unsigned int)f2bf(d) << 16);
            *reinterpret_cast<uint2*>(Wt + (size_t)n * D + k0) = r;
        }
        return;
    }
    // zero gcnt
    int i = (b - nConvF - nConvW) * 256 + t;
    if (i < K) gcnt[i] = 0;
}

// ---------------------------------------------------------------------------
// scatterB (self-contained, fixed regions): per-block LDS hist over own
// chunk -> one global atomic claim per nonzero bin -> LDS-cursor scatter of
// packed (src<<4)|dstLocal into group region [k*CAPG, k*CAPG+CAPG).
// ---------------------------------------------------------------------------
__global__ __launch_bounds__(256) void scatterB_kernel(
    const int* __restrict__ src, const int* __restrict__ dst,
    int* __restrict__ gcnt, int* __restrict__ csrPacked,
    int E, int K, int chunk)
{
    __shared__ int h[KMAX4];     // counts, then absolute cursors
    const int b = blockIdx.x, t = threadIdx.x;
    for (int i = t; i < K; i += 256) h[i] = 0;
    __syncthreads();
    const int beg = b * chunk;
    const int end = min(beg + chunk, E);
    for (int i = beg + t; i < end; i += 256)
        atomicAdd(&h[dst[i] >> GSHIFT], 1);
    __syncthreads();
    for (int i = t; i < K; i += 256) {
        int c = h[i];
        h[i] = c ? atomicAdd(&gcnt[i], c) : 0;   // claim run; h = abs base in region
    }
    __syncthreads();
    for (int i = beg + t; i < end; i += 256) {
        int d = dst[i];
        int k = d >> GSHIFT;
        int r = atomicAdd(&h[k], 1);             // LDS atomic, absolute slot
        if (r < CAPG)
            csrPacked[(size_t)k * CAPG + r] = (src[i] << GSHIFT) | (d & (GSIZE - 1));
    }
}

// ---------------------------------------------------------------------------
// Fused in-LDS sort + aggregate + GEMM at 16-node granularity.
// Block b owns group b = nodes [16b,16b+16), edges csrPacked[b*CAPG .. +cnt).
// P0: counting sort of the group's packed edges into lsrc (LDS).
// P1: gather: 4 waves x 4 nodes; half-wave edge split (lanes 0-31 even edges,
//     32-63 odd), uint4 loads (8 bf16 cols/lane), fp32 acc, shfl_xor merge,
//     bf16 row -> LDS A[16][264].
// P2: GEMM 16x256 @ 256x256 MFMA; wave w owns col-tiles [4w,4w+4);
//     + bias + ReLU -> out (fp32).
// LDS ~16.8 KB -> wave-limited occupancy, gather concurrency preserved.
// ---------------------------------------------------------------------------
__global__ __launch_bounds__(256) void agg_gemm_kernel(
    const unsigned short* __restrict__ fbf,
    const int* __restrict__ csrPacked,
    const int* __restrict__ gcnt,
    const unsigned short* __restrict__ Wt,
    const float* __restrict__ bias,
    float* __restrict__ out, int N)
{
    __shared__ int lsrc[CAPG];
    __shared__ int nBeg[TN], nCnt[TN], nCur[TN];
    __shared__ unsigned short A[TN][D + 8];    // 8448 B, +8 pad

    const int blk  = blockIdx.x;
    const int t    = threadIdx.x;
    const int wave = t >> 6;
    const int lane = t & 63;
    const int sub  = lane & 31;
    const int half = lane >> 5;
    const int node0 = blk * TN;
    const size_t colOff = (size_t)(sub << 3);

    const size_t beg = (size_t)blk * CAPG;
    const int cnt = min(gcnt[blk], CAPG);

    // ---- P0: counting sort into lsrc grouped by local node ----
    if (t < TN) nCnt[t] = 0;
    __syncthreads();
    for (int i = t; i < cnt; i += 256)
        atomicAdd(&nCnt[csrPacked[beg + i] & (GSIZE - 1)], 1);
    __syncthreads();
    if (t == 0) {
        int run = 0;
        for (int j = 0; j < TN; ++j) { nBeg[j] = run; run += nCnt[j]; }
    }
    __syncthreads();
    if (t < TN) nCur[t] = nBeg[t];
    __syncthreads();
    for (int i = t; i < cnt; i += 256) {
        int p = csrPacked[beg + i];
        int r = atomicAdd(&nCur[p & (GSIZE - 1)], 1);
        lsrc[r] = p >> GSHIFT;
    }
    __syncthreads();

    // ---- P1: gather 4 nodes per wave ----
    for (int ni = 0; ni < 4; ++ni) {
        const int l = (wave << 2) + ni;
        const int node = node0 + l;
        float a0 = 0.f, a1 = 0.f, a2 = 0.f, a3 = 0.f;
        float a4 = 0.f, a5 = 0.f, a6 = 0.f, a7 = 0.f;
        if (node < N) {
            const int b0 = nBeg[l];
            const int c0 = nCnt[l];
            int j = 0;
            for (; j + 3 < c0; j += 4) {
                int s0 = lsrc[b0 + j + half];
                int s1 = lsrc[b0 + j + 2 + half];
                uint4 v0 = *reinterpret_cast<const uint4*>(fbf + ((size_t)s0 << 8) + colOff);
                uint4 v1 = *reinterpret_cast<const uint4*>(fbf + ((size_t)s1 << 8) + colOff);
                a0 += bf_lo(v0.x); a1 += bf_hi(v0.x); a2 += bf_lo(v0.y); a3 += bf_hi(v0.y);
                a4 += bf_lo(v0.z); a5 += bf_hi(v0.z); a6 += bf_lo(v0.w); a7 += bf_hi(v0.w);
                a0 += bf_lo(v1.x); a1 += bf_hi(v1.x); a2 += bf_lo(v1.y); a3 += bf_hi(v1.y);
                a4 += bf_lo(v1.z); a5 += bf_hi(v1.z); a6 += bf_lo(v1.w); a7 += bf_hi(v1.w);
            }
            if (j + 1 < c0) {
                int s0 = lsrc[b0 + j + half];
                uint4 v0 = *reinterpret_cast<const uint4*>(fbf + ((size_t)s0 << 8) + colOff);
                a0 += bf_lo(v0.x); a1 += bf_hi(v0.x); a2 += bf_lo(v0.y); a3 += bf_hi(v0.y);
                a4 += bf_lo(v0.z); a5 += bf_hi(v0.z); a6 += bf_lo(v0.w); a7 += bf_hi(v0.w);
                j += 2;
            }
            if (j < c0 && half == 0) {
                int s0 = lsrc[b0 + j];
                uint4 v0 = *reinterpret_cast<const uint4*>(fbf + ((size_t)s0 << 8) + colOff);
                a0 += bf_lo(v0.x); a1 += bf_hi(v0.x); a2 += bf_lo(v0.y); a3 += bf_hi(v0.y);
                a4 += bf_lo(v0.z); a5 += bf_hi(v0.z); a6 += bf_lo(v0.w); a7 += bf_hi(v0.w);
            }
        }
        a0 += __shfl_xor(a0, 32); a1 += __shfl_xor(a1, 32);
        a2 += __shfl_xor(a2, 32); a3 += __shfl_xor(a3, 32);
        a4 += __shfl_xor(a4, 32); a5 += __shfl_xor(a5, 32);
        a6 += __shfl_xor(a6, 32); a7 += __shfl_xor(a7, 32);
        if (half == 0) {
            uint4 r;
            r.x = (unsigned int)f2bf(a0) | ((unsigned int)f2bf(a1) << 16);
            r.y = (unsigned int)f2bf(a2) | ((unsigned int)f2bf(a3) << 16);
            r.z = (unsigned int)f2bf(a4) | ((unsigned int)f2bf(a5) << 16);
            r.w = (unsigned int)f2bf(a6) | ((unsigned int)f2bf(a7) << 16);
            *reinterpret_cast<uint4*>(&A[l][sub << 3]) = r;
        }
    }
    __syncthreads();

    // ---- P2: GEMM 16x256 ----
    const int lr = lane & 15;
    const int lg = lane >> 4;

    bf16x8 afr[8];
#pragma unroll
    for (int ks = 0; ks < 8; ++ks)
        afr[ks] = *reinterpret_cast<const bf16x8*>(&A[lr][ks * 32 + lg * 8]);

#pragma unroll
    for (int c = 0; c < 4; ++c) {
        const int ct = (wave << 2) + c;
        f32x4 acc = {0.f, 0.f, 0.f, 0.f};
        const unsigned short* bp = Wt + (size_t)(ct * 16 + lr) * D + lg * 8;
#pragma unroll
        for (int ks = 0; ks < 8; ++ks) {
            bf16x8 bfr = *reinterpret_cast<const bf16x8*>(bp + ks * 32);
            acc = __builtin_amdgcn_mfma_f32_16x16x32_bf16(afr[ks], bfr, acc, 0, 0, 0);
        }
        const float bv = bias[ct * 16 + lr];
#pragma unroll
        for (int jj = 0; jj < 4; ++jj) {
            int row = node0 + lg * 4 + jj;
            if (row < N) {
                float v = acc[jj] + bv;
                out[(size_t)row * D + ct * 16 + lr] = v > 0.f ? v : 0.f;
            }
        }
    }
}

// ---------------------------------------------------------------------------
// Fallback kernels (ws too small): direct atomic scatter + VALU linear.
// ---------------------------------------------------------------------------
__global__ __launch_bounds__(256) void scatter_kernel(
    const float* __restrict__ feature, const int* __restrict__ src,
    const int* __restrict__ dst, float* __restrict__ agg, int E)
{
    int edge = blockIdx.x * (blockDim.x >> 6) + (threadIdx.x >> 6);
    int lane = threadIdx.x & 63;
    if (edge >= E) return;
    int s = src[edge];
    int d = dst[edge];
    const float4 v = *reinterpret_cast<const float4*>(feature + (size_t)s * D + lane * 4);
    float* o = agg + (size_t)d * D + lane * 4;
    atomicAdd(o + 0, v.x);
    atomicAdd(o + 1, v.y);
    atomicAdd(o + 2, v.z);
    atomicAdd(o + 3, v.w);
}

#define BM 32
__global__ __launch_bounds__(256) void linear_relu_kernel(
    float* __restrict__ h, const float* __restrict__ W,
    const float* __restrict__ b, int n_nodes)
{
    __shared__ float sA[BM][D];
    const int node0 = blockIdx.x * BM;
    const int t = threadIdx.x;
    for (int m = 0; m < BM; ++m) {
        int nd = node0 + m;
        sA[m][t] = (nd < n_nodes) ? h[(size_t)nd * D + t] : 0.0f;
    }
    __syncthreads();
    float acc[BM];
#pragma unroll
    for (int m = 0; m < BM; ++m) acc[m] = 0.0f;
    for (int kk = 0; kk < D; ++kk) {
        float w = W[kk * D + t];
#pragma unroll
        for (int m = 0; m < BM; ++m) acc[m] += sA[m][kk] * w;
    }
    const float bias = b[t];
    for (int m = 0; m < BM; ++m) {
        int nd = node0 + m;
        if (nd < n_nodes) {
            float v = acc[m] + bias;
            h[(size_t)nd * D + t] = v > 0.0f ? v : 0.0f;
        }
    }
}

// ---------------------------------------------------------------------------
extern "C" void kernel_launch(void* const* d_in, const int* in_sizes, int n_in,
                              void* d_out, int out_size, void* d_ws, size_t ws_size,
                              hipStream_t stream)
{
    const float* feature = (const float*)d_in[0];
    const int*   src     = (const int*)d_in[1];
    const int*   dst     = (const int*)d_in[2];
    const float* W       = (const float*)d_in[3];
    const float* b       = (const float*)d_in[4];
    float*       out     = (float*)d_out;

    const int E = in_sizes[1];
    const int N = in_sizes[0] / D;
    const int K = (N + GSIZE - 1) >> GSHIFT;        // 16-node groups
    const int chunk = (E + NB_P - 1) / NB_P;

    // ---- workspace layout -------------------------------------------------
    size_t off = 0;
    auto alloc = [&](size_t bytes, size_t align) {
        off = (off + align - 1) / align * align;
        size_t r = off; off += bytes; return r;
    };
    size_t o_gcnt   = alloc((size_t)K * 4, 16);
    size_t o_packed = alloc((size_t)K * CAPG * 4, 16);
    size_t o_wt     = alloc((size_t)D * D * 2, 16);
    size_t o_fbf    = alloc((size_t)N * D * 2, 16);
    size_t need_full = off;

    char* ws = (char*)d_ws;

    // capacity guard: mean edges/group * 2 + 64 must fit CAPG
    // (E/K = 512 here -> 1088 <= 2048; actual max group ~615 at 4.5 sigma)
    const bool cap_ok = ((long)E / K) * 2 + 64 <= CAPG;

    if (ws_size >= need_full && K <= KMAX4 && cap_ok) {
        int* gcnt      = (int*)(ws + o_gcnt);
        int* csrPacked = (int*)(ws + o_packed);
        unsigned short* Wt  = (unsigned short*)(ws + o_wt);
        unsigned short* fbf = (unsigned short*)(ws + o_fbf);

        const long n8 = (long)N * D / 8;
        const int nConvF = (int)((n8 + 255) / 256);
        const int nConvW = (D * D / 4 + 255) / 256;
        const int nZero  = (K + 255) / 256;

        prep_kernel<<<nConvF + nConvW + nZero, 256, 0, stream>>>(
            feature, fbf, n8, W, Wt, gcnt, K, nConvF, nConvW);

        scatterB_kernel<<<NB_P, 256, 0, stream>>>(
            src, dst, gcnt, csrPacked, E, K, chunk);

        agg_gemm_kernel<<<(N + TN - 1) / TN, 256, 0, stream>>>(
            fbf, csrPacked, gcnt, Wt, b, out, N);
    } else {
        hipMemsetAsync(d_out, 0, (size_t)out_size * sizeof(float), stream);
        scatter_kernel<<<(E + 3) / 4, 256, 0, stream>>>(feature, src, dst, out, E);
        linear_relu_kernel<<<(N + BM - 1) / BM, 256, 0, stream>>>(out, W, b, N);
    }
}

// Round 13
// 408.682 us; speedup vs baseline: 27.0399x; 1.0001x over previous
//
#include <hip/hip_runtime.h>

#define D 256
#define GSHIFT 4
#define GSIZE 16          // nodes per group (= nodes per agg_gemm block)
#define KMAX4 6400        // max groups (scatter LDS hist: 25.6 KB)
#define NB_P 256          // partition blocks
#define TN 16             // nodes per agg_gemm block
#define CAPG 2048         // fixed region capacity per group (mean 512 here)

using bf16x8 = __attribute__((ext_vector_type(8))) short;
using f32x4  = __attribute__((ext_vector_type(4))) float;

__device__ inline float bf_lo(unsigned int u) {
    return __builtin_bit_cast(float, u << 16);
}
__device__ inline float bf_hi(unsigned int u) {
    return __builtin_bit_cast(float, u & 0xffff0000u);
}
__device__ inline unsigned short f2bf(float f) {
    unsigned int x = __builtin_bit_cast(unsigned int, f);
    unsigned int r = (x + 0x7fffu + ((x >> 16) & 1u)) >> 16;   // RNE
    return (unsigned short)r;
}

// ---------------------------------------------------------------------------
// part_kernel: scatter-partition || conv_feature || conv_w, fused via
// blockIdx role split. Scatter blocks come first (longest pole, and they
// claim gcnt regions early). gcnt must be zeroed beforehand (memset).
// Conv blocks pay the 25.6 KB LDS occupancy tax (6 blocks/CU) but their
// 153 MB streaming burst hides under the scatter phase.
// ---------------------------------------------------------------------------
__global__ __launch_bounds__(256) void part_kernel(
    const int* __restrict__ src, const int* __restrict__ dst,
    int* __restrict__ gcnt, int* __restrict__ csrPacked,
    const float* __restrict__ feature, unsigned short* __restrict__ fbf, long n8,
    const float* __restrict__ W, unsigned short* __restrict__ Wt,
    int E, int K, int chunk, int nConvF)
{
    __shared__ int h[KMAX4];     // counts, then absolute cursors
    const int b = blockIdx.x, t = threadIdx.x;

    if (b < NB_P) {
        // ---- scatter role ----
        for (int i = t; i < K; i += 256) h[i] = 0;
        __syncthreads();
        const int beg = b * chunk;
        const int end = min(beg + chunk, E);
        for (int i = beg + t; i < end; i += 256)
            atomicAdd(&h[dst[i] >> GSHIFT], 1);
        __syncthreads();
        for (int i = t; i < K; i += 256) {
            int c = h[i];
            h[i] = c ? atomicAdd(&gcnt[i], c) : 0;   // claim run; h = abs base
        }
        __syncthreads();
        for (int i = beg + t; i < end; i += 256) {
            int d = dst[i];
            int k = d >> GSHIFT;
            int r = atomicAdd(&h[k], 1);             // LDS atomic, absolute slot
            if (r < CAPG)
                csrPacked[(size_t)k * CAPG + r] = (src[i] << GSHIFT) | (d & (GSIZE - 1));
        }
        return;
    }
    if (b < NB_P + nConvF) {
        // ---- feature -> bf16 ----
        long i = (long)(b - NB_P) * 256 + t;
        if (i < n8) {
            const float4* p = reinterpret_cast<const float4*>(feature + i * 8);
            float4 v0 = p[0], v1 = p[1];
            uint4 r;
            r.x = (unsigned int)f2bf(v0.x) | ((unsigned int)f2bf(v0.y) << 16);
            r.y = (unsigned int)f2bf(v0.z) | ((unsigned int)f2bf(v0.w) << 16);
            r.z = (unsigned int)f2bf(v1.x) | ((unsigned int)f2bf(v1.y) << 16);
            r.w = (unsigned int)f2bf(v1.z) | ((unsigned int)f2bf(v1.w) << 16);
            *reinterpret_cast<uint4*>(fbf + i * 8) = r;
        }
        return;
    }
    // ---- W -> Wt (bf16, transposed) ----
    int i = (b - NB_P - nConvF) * 256 + t;
    if (i < D * D / 4) {
        int n  = i >> 6;
        int k0 = (i & 63) * 4;
        float a  = W[(size_t)(k0 + 0) * D + n];
        float bb = W[(size_t)(k0 + 1) * D + n];
        float c  = W[(size_t)(k0 + 2) * D + n];
        float d  = W[(size_t)(k0 + 3) * D + n];
        uint2 r;
        r.x = (unsigned int)f2bf(a) | ((unsigned int)f2bf(bb) << 16);
        r.y = (unsigned int)f2bf(c) | ((unsigned int)f2bf(d) << 16);
        *reinterpret_cast<uint2*>(Wt + (size_t)n * D + k0) = r;
    }
}

// ---------------------------------------------------------------------------
// Fused in-LDS sort + aggregate + GEMM at 16-node granularity.
// Block b owns group b = nodes [16b,16b+16), edges csrPacked[b*CAPG .. +cnt).
// P0: counting sort of the group's packed edges into lsrc (LDS).
// P1: gather: 4 waves x 4 nodes; half-wave edge split (lanes 0-31 even edges,
//     32-63 odd), uint4 loads (8 bf16 cols/lane), fp32 acc, shfl_xor merge,
//     bf16 row -> LDS A[16][264].
// P2: GEMM 16x256 @ 256x256 MFMA; wave w owns col-tiles [4w,4w+4);
//     + bias + ReLU -> out (fp32).
// ---------------------------------------------------------------------------
__global__ __launch_bounds__(256) void agg_gemm_kernel(
    const unsigned short* __restrict__ fbf,
    const int* __restrict__ csrPacked,
    const int* __restrict__ gcnt,
    const unsigned short* __restrict__ Wt,
    const float* __restrict__ bias,
    float* __restrict__ out, int N)
{
    __shared__ int lsrc[CAPG];
    __shared__ int nBeg[TN], nCnt[TN], nCur[TN];
    __shared__ unsigned short A[TN][D + 8];    // 8448 B, +8 pad

    const int blk  = blockIdx.x;
    const int t    = threadIdx.x;
    const int wave = t >> 6;
    const int lane = t & 63;
    const int sub  = lane & 31;
    const int half = lane >> 5;
    const int node0 = blk * TN;
    const size_t colOff = (size_t)(sub << 3);

    const size_t beg = (size_t)blk * CAPG;
    const int cnt = min(gcnt[blk], CAPG);

    // ---- P0: counting sort into lsrc grouped by local node ----
    if (t < TN) nCnt[t] = 0;
    __syncthreads();
    for (int i = t; i < cnt; i += 256)
        atomicAdd(&nCnt[csrPacked[beg + i] & (GSIZE - 1)], 1);
    __syncthreads();
    if (t == 0) {
        int run = 0;
        for (int j = 0; j < TN; ++j) { nBeg[j] = run; run += nCnt[j]; }
    }
    __syncthreads();
    if (t < TN) nCur[t] = nBeg[t];
    __syncthreads();
    for (int i = t; i < cnt; i += 256) {
        int p = csrPacked[beg + i];
        int r = atomicAdd(&nCur[p & (GSIZE - 1)], 1);
        lsrc[r] = p >> GSHIFT;
    }
    __syncthreads();

    // ---- P1: gather 4 nodes per wave ----
    for (int ni = 0; ni < 4; ++ni) {
        const int l = (wave << 2) + ni;
        const int node = node0 + l;
        float a0 = 0.f, a1 = 0.f, a2 = 0.f, a3 = 0.f;
        float a4 = 0.f, a5 = 0.f, a6 = 0.f, a7 = 0.f;
        if (node < N) {
            const int b0 = nBeg[l];
            const int c0 = nCnt[l];
            int j = 0;
            for (; j + 3 < c0; j += 4) {
                int s0 = lsrc[b0 + j + half];
                int s1 = lsrc[b0 + j + 2 + half];
                uint4 v0 = *reinterpret_cast<const uint4*>(fbf + ((size_t)s0 << 8) + colOff);
                uint4 v1 = *reinterpret_cast<const uint4*>(fbf + ((size_t)s1 << 8) + colOff);
                a0 += bf_lo(v0.x); a1 += bf_hi(v0.x); a2 += bf_lo(v0.y); a3 += bf_hi(v0.y);
                a4 += bf_lo(v0.z); a5 += bf_hi(v0.z); a6 += bf_lo(v0.w); a7 += bf_hi(v0.w);
                a0 += bf_lo(v1.x); a1 += bf_hi(v1.x); a2 += bf_lo(v1.y); a3 += bf_hi(v1.y);
                a4 += bf_lo(v1.z); a5 += bf_hi(v1.z); a6 += bf_lo(v1.w); a7 += bf_hi(v1.w);
            }
            if (j + 1 < c0) {
                int s0 = lsrc[b0 + j + half];
                uint4 v0 = *reinterpret_cast<const uint4*>(fbf + ((size_t)s0 << 8) + colOff);
                a0 += bf_lo(v0.x); a1 += bf_hi(v0.x); a2 += bf_lo(v0.y); a3 += bf_hi(v0.y);
                a4 += bf_lo(v0.z); a5 += bf_hi(v0.z); a6 += bf_lo(v0.w); a7 += bf_hi(v0.w);
                j += 2;
            }
            if (j < c0 && half == 0) {
                int s0 = lsrc[b0 + j];
                uint4 v0 = *reinterpret_cast<const uint4*>(fbf + ((size_t)s0 << 8) + colOff);
                a0 += bf_lo(v0.x); a1 += bf_hi(v0.x); a2 += bf_lo(v0.y); a3 += bf_hi(v0.y);
                a4 += bf_lo(v0.z); a5 += bf_hi(v0.z); a6 += bf_lo(v0.w); a7 += bf_hi(v0.w);
            }
        }
        a0 += __shfl_xor(a0, 32); a1 += __shfl_xor(a1, 32);
        a2 += __shfl_xor(a2, 32); a3 += __shfl_xor(a3, 32);
        a4 += __shfl_xor(a4, 32); a5 += __shfl_xor(a5, 32);
        a6 += __shfl_xor(a6, 32); a7 += __shfl_xor(a7, 32);
        if (half == 0) {
            uint4 r;
            r.x = (unsigned int)f2bf(a0) | ((unsigned int)f2bf(a1) << 16);
            r.y = (unsigned int)f2bf(a2) | ((unsigned int)f2bf(a3) << 16);
            r.z = (unsigned int)f2bf(a4) | ((unsigned int)f2bf(a5) << 16);
            r.w = (unsigned int)f2bf(a6) | ((unsigned int)f2bf(a7) << 16);
            *reinterpret_cast<uint4*>(&A[l][sub << 3]) = r;
        }
    }
    __syncthreads();

    // ---- P2: GEMM 16x256 ----
    const int lr = lane & 15;
    const int lg = lane >> 4;

    bf16x8 afr[8];
#pragma unroll
    for (int ks = 0; ks < 8; ++ks)
        afr[ks] = *reinterpret_cast<const bf16x8*>(&A[lr][ks * 32 + lg * 8]);

#pragma unroll
    for (int c = 0; c < 4; ++c) {
        const int ct = (wave << 2) + c;
        f32x4 acc = {0.f, 0.f, 0.f, 0.f};
        const unsigned short* bp = Wt + (size_t)(ct * 16 + lr) * D + lg * 8;
#pragma unroll
        for (int ks = 0; ks < 8; ++ks) {
            bf16x8 bfr = *reinterpret_cast<const bf16x8*>(bp + ks * 32);
            acc = __builtin_amdgcn_mfma_f32_16x16x32_bf16(afr[ks], bfr, acc, 0, 0, 0);
        }
        const float bv = bias[ct * 16 + lr];
#pragma unroll
        for (int jj = 0; jj < 4; ++jj) {
            int row = node0 + lg * 4 + jj;
            if (row < N) {
                float v = acc[jj] + bv;
                out[(size_t)row * D + ct * 16 + lr] = v > 0.f ? v : 0.f;
            }
        }
    }
}

// ---------------------------------------------------------------------------
// Fallback kernels (ws too small): direct atomic scatter + VALU linear.
// ---------------------------------------------------------------------------
__global__ __launch_bounds__(256) void scatter_kernel(
    const float* __restrict__ feature, const int* __restrict__ src,
    const int* __restrict__ dst, float* __restrict__ agg, int E)
{
    int edge = blockIdx.x * (blockDim.x >> 6) + (threadIdx.x >> 6);
    int lane = threadIdx.x & 63;
    if (edge >= E) return;
    int s = src[edge];
    int d = dst[edge];
    const float4 v = *reinterpret_cast<const float4*>(feature + (size_t)s * D + lane * 4);
    float* o = agg + (size_t)d * D + lane * 4;
    atomicAdd(o + 0, v.x);
    atomicAdd(o + 1, v.y);
    atomicAdd(o + 2, v.z);
    atomicAdd(o + 3, v.w);
}

#define BM 32
__global__ __launch_bounds__(256) void linear_relu_kernel(
    float* __restrict__ h, const float* __restrict__ W,
    const float* __restrict__ b, int n_nodes)
{
    __shared__ float sA[BM][D];
    const int node0 = blockIdx.x * BM;
    const int t = threadIdx.x;
    for (int m = 0; m < BM; ++m) {
        int nd = node0 + m;
        sA[m][t] = (nd < n_nodes) ? h[(size_t)nd * D + t] : 0.0f;
    }
    __syncthreads();
    float acc[BM];
#pragma unroll
    for (int m = 0; m < BM; ++m) acc[m] = 0.0f;
    for (int kk = 0; kk < D; ++kk) {
        float w = W[kk * D + t];
#pragma unroll
        for (int m = 0; m < BM; ++m) acc[m] += sA[m][kk] * w;
    }
    const float bias = b[t];
    for (int m = 0; m < BM; ++m) {
        int nd = node0 + m;
        if (nd < n_nodes) {
            float v = acc[m] + bias;
            h[(size_t)nd * D + t] = v > 0.0f ? v : 0.0f;
        }
    }
}

// ---------------------------------------------------------------------------
extern "C" void kernel_launch(void* const* d_in, const int* in_sizes, int n_in,
                              void* d_out, int out_size, void* d_ws, size_t ws_size,
                              hipStream_t stream)
{
    const float* feature = (const float*)d_in[0];
    const int*   src     = (const int*)d_in[1];
    const int*   dst     = (const int*)d_in[2];
    const float* W       = (const float*)d_in[3];
    const float* b       = (const float*)d_in[4];
    float*       out     = (float*)d_out;

    const int E = in_sizes[1];
    const int N = in_sizes[0] / D;
    const int K = (N + GSIZE - 1) >> GSHIFT;        // 16-node groups
    const int chunk = (E + NB_P - 1) / NB_P;

    // ---- workspace layout -------------------------------------------------
    size_t off = 0;
    auto alloc = [&](size_t bytes, size_t align) {
        off = (off + align - 1) / align * align;
        size_t r = off; off += bytes; return r;
    };
    size_t o_gcnt   = alloc((size_t)K * 4, 16);
    size_t o_packed = alloc((size_t)K * CAPG * 4, 16);
    size_t o_wt     = alloc((size_t)D * D * 2, 16);
    size_t o_fbf    = alloc((size_t)N * D * 2, 16);
    size_t need_full = off;

    char* ws = (char*)d_ws;

    // capacity guard: mean edges/group * 2 + 64 must fit CAPG
    const bool cap_ok = ((long)E / K) * 2 + 64 <= CAPG;

    if (ws_size >= need_full && K <= KMAX4 && cap_ok) {
        int* gcnt      = (int*)(ws + o_gcnt);
        int* csrPacked = (int*)(ws + o_packed);
        unsigned short* Wt  = (unsigned short*)(ws + o_wt);
        unsigned short* fbf = (unsigned short*)(ws + o_fbf);

        const long n8 = (long)N * D / 8;
        const int nConvF = (int)((n8 + 255) / 256);
        const int nConvW = (D * D / 4 + 255) / 256;

        hipMemsetAsync(gcnt, 0, (size_t)K * 4, stream);

        part_kernel<<<NB_P + nConvF + nConvW, 256, 0, stream>>>(
            src, dst, gcnt, csrPacked, feature, fbf, n8, W, Wt,
            E, K, chunk, nConvF);

        agg_gemm_kernel<<<(N + TN - 1) / TN, 256, 0, stream>>>(
            fbf, csrPacked, gcnt, Wt, b, out, N);
    } else {
        hipMemsetAsync(d_out, 0, (size_t)out_size * sizeof(float), stream);
        scatter_kernel<<<(E + 3) / 4, 256, 0, stream>>>(feature, src, dst, out, E);
        linear_relu_kernel<<<(N + BM - 1) / BM, 256, 0, stream>>>(out, W, b, N);
    }
}

// Round 14
// 391.983 us; speedup vs baseline: 28.1918x; 1.0426x over previous
//
#include <hip/hip_runtime.h>

#define D 256
#define GSHIFT 4
#define GSIZE 16          // nodes per group (= nodes per agg_gemm block)
#define TN 16             // nodes per agg_gemm block
#define CAPG2 1024        // csrB region per group (mean 512, guard mean+8sig+16)
#define CSHIFT 8
#define CBIN 256          // nodes per coarse bin
#define GPB 16            // groups per coarse bin
#define NCMAX 512         // max coarse bins (pass-A LDS hist 2 KB)
#define CAPC 9216         // csrA region per coarse bin (mean 8192)
#define NB_P 256          // pass-A scatter blocks

using bf16x8 = __attribute__((ext_vector_type(8))) short;
using f32x4  = __attribute__((ext_vector_type(4))) float;

__device__ inline float bf_lo(unsigned int u) {
    return __builtin_bit_cast(float, u << 16);
}
__device__ inline float bf_hi(unsigned int u) {
    return __builtin_bit_cast(float, u & 0xffff0000u);
}
__device__ inline unsigned short f2bf(float f) {
    unsigned int x = __builtin_bit_cast(unsigned int, f);
    unsigned int r = (x + 0x7fffu + ((x >> 16) & 1u)) >> 16;   // RNE
    return (unsigned short)r;
}

// ---------------------------------------------------------------------------
// Pass A: coarse scatter (dst>>8, 391 bins) || conv_feature || conv_w.
// Coarse bins keep the active write-line set ~800 KB/XCD (<< 4 MB L2), so
// partial 4B writes coalesce in L2 -> ~1x HBM write amplification.
// csrA entry: (src<<8) | (dst&255).
// ---------------------------------------------------------------------------
__global__ __launch_bounds__(256) void part_kernel(
    const int* __restrict__ src, const int* __restrict__ dst,
    int* __restrict__ gcntC, int* __restrict__ csrA,
    const float* __restrict__ feature, unsigned short* __restrict__ fbf, long n8,
    const float* __restrict__ W, unsigned short* __restrict__ Wt,
    int E, int NC, int chunk, int nConvF)
{
    __shared__ int h[NCMAX];     // counts, then absolute cursors
    const int b = blockIdx.x, t = threadIdx.x;

    if (b < NB_P) {
        // ---- coarse scatter role ----
        for (int i = t; i < NC; i += 256) h[i] = 0;
        __syncthreads();
        const int beg = b * chunk;
        const int end = min(beg + chunk, E);
        for (int i = beg + t; i < end; i += 256)
            atomicAdd(&h[dst[i] >> CSHIFT], 1);
        __syncthreads();
        for (int i = t; i < NC; i += 256) {
            int c = h[i];
            h[i] = c ? atomicAdd(&gcntC[i], c) : 0;   // claim run; h = base in region
        }
        __syncthreads();
        for (int i = beg + t; i < end; i += 256) {
            int d = dst[i];
            int c = d >> CSHIFT;
            int r = atomicAdd(&h[c], 1);              // LDS atomic, offset in region
            if (r < CAPC)
                csrA[(size_t)c * CAPC + r] = (src[i] << CSHIFT) | (d & (CBIN - 1));
        }
        return;
    }
    if (b < NB_P + nConvF) {
        // ---- feature -> bf16 ----
        long i = (long)(b - NB_P) * 256 + t;
        if (i < n8) {
            const float4* p = reinterpret_cast<const float4*>(feature + i * 8);
            float4 v0 = p[0], v1 = p[1];
            uint4 r;
            r.x = (unsigned int)f2bf(v0.x) | ((unsigned int)f2bf(v0.y) << 16);
            r.y = (unsigned int)f2bf(v0.z) | ((unsigned int)f2bf(v0.w) << 16);
            r.z = (unsigned int)f2bf(v1.x) | ((unsigned int)f2bf(v1.y) << 16);
            r.w = (unsigned int)f2bf(v1.z) | ((unsigned int)f2bf(v1.w) << 16);
            *reinterpret_cast<uint4*>(fbf + i * 8) = r;
        }
        return;
    }
    // ---- W -> Wt (bf16, transposed) ----
    int i = (b - NB_P - nConvF) * 256 + t;
    if (i < D * D / 4) {
        int n  = i >> 6;
        int k0 = (i & 63) * 4;
        float a  = W[(size_t)(k0 + 0) * D + n];
        float bb = W[(size_t)(k0 + 1) * D + n];
        float c  = W[(size_t)(k0 + 2) * D + n];
        float d  = W[(size_t)(k0 + 3) * D + n];
        uint2 r;
        r.x = (unsigned int)f2bf(a) | ((unsigned int)f2bf(bb) << 16);
        r.y = (unsigned int)f2bf(c) | ((unsigned int)f2bf(d) << 16);
        *reinterpret_cast<uint2*>(Wt + (size_t)n * D + k0) = r;
    }
}

// ---------------------------------------------------------------------------
// Pass B: regroup. One block per coarse bin: LDS counting sort of the bin's
// ~8200 edges by 16-node group, then fully-coalesced run writes into csrB
// (region stride CAPG2 per group) + exact per-group counts into gcnt.
// csrB entry: (src<<4) | (dst&15).
// ---------------------------------------------------------------------------
__global__ __launch_bounds__(256) void regroup_kernel(
    const int* __restrict__ csrA, const int* __restrict__ gcntC,
    int* __restrict__ csrB, int* __restrict__ gcnt, int K)
{
    __shared__ int sorted[CAPC];               // 36.9 KB
    __shared__ int h2[GPB], b2[GPB], cur2[GPB];
    const int c = blockIdx.x, t = threadIdx.x;
    const size_t rbeg = (size_t)c * CAPC;
    const int cnt = min(gcntC[c], CAPC);

    if (t < GPB) h2[t] = 0;
    __syncthreads();
    for (int i = t; i < cnt; i += 256)
        atomicAdd(&h2[(csrA[rbeg + i] >> GSHIFT) & (GPB - 1)], 1);
    __syncthreads();
    if (t == 0) {
        int run = 0;
        for (int j = 0; j < GPB; ++j) { b2[j] = run; run += h2[j]; }
    }
    __syncthreads();
    if (t < GPB) cur2[t] = b2[t];
    __syncthreads();
    for (int i = t; i < cnt; i += 256) {
        int p = csrA[rbeg + i];
        int r = atomicAdd(&cur2[(p >> GSHIFT) & (GPB - 1)], 1);
        sorted[r] = p;
    }
    __syncthreads();
    // coalesced run writes: consecutive i within a group -> consecutive csrB
    for (int i = t; i < cnt; i += 256) {
        int p = sorted[i];
        int g = (p >> GSHIFT) & (GPB - 1);
        int k = (c << 4) + g;
        int off = i - b2[g];
        if (k < K && off < CAPG2)
            csrB[(size_t)k * CAPG2 + off] = ((p >> CSHIFT) << GSHIFT) | (p & (GSIZE - 1));
    }
    if (t < GPB) {
        int k = (c << 4) + t;
        if (k < K) gcnt[k] = min(h2[t], CAPG2);
    }
}

// ---------------------------------------------------------------------------
// Fused in-LDS sort + aggregate + GEMM at 16-node granularity.
// Block b owns group b = nodes [16b,16b+16), edges csrB[b*CAPG2 .. +cnt).
// P0: counting sort of the group's packed edges into lsrc (LDS).
// P1: gather: 4 waves x 4 nodes; half-wave edge split, uint4 loads
//     (8 bf16 cols/lane), fp32 acc, shfl_xor merge, bf16 row -> LDS A.
// P2: GEMM 16x256 @ 256x256 MFMA + bias + ReLU -> out (fp32).
// LDS ~12.8 KB.
// ---------------------------------------------------------------------------
__global__ __launch_bounds__(256) void agg_gemm_kernel(
    const unsigned short* __restrict__ fbf,
    const int* __restrict__ csrB,
    const int* __restrict__ gcnt,
    const unsigned short* __restrict__ Wt,
    const float* __restrict__ bias,
    float* __restrict__ out, int N)
{
    __shared__ int lsrc[CAPG2];
    __shared__ int nBeg[TN], nCnt[TN], nCur[TN];
    __shared__ unsigned short A[TN][D + 8];    // 8448 B, +8 pad

    const int blk  = blockIdx.x;
    const int t    = threadIdx.x;
    const int wave = t >> 6;
    const int lane = t & 63;
    const int sub  = lane & 31;
    const int half = lane >> 5;
    const int node0 = blk * TN;
    const size_t colOff = (size_t)(sub << 3);

    const size_t beg = (size_t)blk * CAPG2;
    const int cnt = min(gcnt[blk], CAPG2);

    // ---- P0: counting sort into lsrc grouped by local node ----
    if (t < TN) nCnt[t] = 0;
    __syncthreads();
    for (int i = t; i < cnt; i += 256)
        atomicAdd(&nCnt[csrB[beg + i] & (GSIZE - 1)], 1);
    __syncthreads();
    if (t == 0) {
        int run = 0;
        for (int j = 0; j < TN; ++j) { nBeg[j] = run; run += nCnt[j]; }
    }
    __syncthreads();
    if (t < TN) nCur[t] = nBeg[t];
    __syncthreads();
    for (int i = t; i < cnt; i += 256) {
        int p = csrB[beg + i];
        int r = atomicAdd(&nCur[p & (GSIZE - 1)], 1);
        lsrc[r] = p >> GSHIFT;
    }
    __syncthreads();

    // ---- P1: gather 4 nodes per wave ----
    for (int ni = 0; ni < 4; ++ni) {
        const int l = (wave << 2) + ni;
        const int node = node0 + l;
        float a0 = 0.f, a1 = 0.f, a2 = 0.f, a3 = 0.f;
        float a4 = 0.f, a5 = 0.f, a6 = 0.f, a7 = 0.f;
        if (node < N) {
            const int b0 = nBeg[l];
            const int c0 = nCnt[l];
            int j = 0;
            for (; j + 3 < c0; j += 4) {
                int s0 = lsrc[b0 + j + half];
                int s1 = lsrc[b0 + j + 2 + half];
                uint4 v0 = *reinterpret_cast<const uint4*>(fbf + ((size_t)s0 << 8) + colOff);
                uint4 v1 = *reinterpret_cast<const uint4*>(fbf + ((size_t)s1 << 8) + colOff);
                a0 += bf_lo(v0.x); a1 += bf_hi(v0.x); a2 += bf_lo(v0.y); a3 += bf_hi(v0.y);
                a4 += bf_lo(v0.z); a5 += bf_hi(v0.z); a6 += bf_lo(v0.w); a7 += bf_hi(v0.w);
                a0 += bf_lo(v1.x); a1 += bf_hi(v1.x); a2 += bf_lo(v1.y); a3 += bf_hi(v1.y);
                a4 += bf_lo(v1.z); a5 += bf_hi(v1.z); a6 += bf_lo(v1.w); a7 += bf_hi(v1.w);
            }
            if (j + 1 < c0) {
                int s0 = lsrc[b0 + j + half];
                uint4 v0 = *reinterpret_cast<const uint4*>(fbf + ((size_t)s0 << 8) + colOff);
                a0 += bf_lo(v0.x); a1 += bf_hi(v0.x); a2 += bf_lo(v0.y); a3 += bf_hi(v0.y);
                a4 += bf_lo(v0.z); a5 += bf_hi(v0.z); a6 += bf_lo(v0.w); a7 += bf_hi(v0.w);
                j += 2;
            }
            if (j < c0 && half == 0) {
                int s0 = lsrc[b0 + j];
                uint4 v0 = *reinterpret_cast<const uint4*>(fbf + ((size_t)s0 << 8) + colOff);
                a0 += bf_lo(v0.x); a1 += bf_hi(v0.x); a2 += bf_lo(v0.y); a3 += bf_hi(v0.y);
                a4 += bf_lo(v0.z); a5 += bf_hi(v0.z); a6 += bf_lo(v0.w); a7 += bf_hi(v0.w);
            }
        }
        a0 += __shfl_xor(a0, 32); a1 += __shfl_xor(a1, 32);
        a2 += __shfl_xor(a2, 32); a3 += __shfl_xor(a3, 32);
        a4 += __shfl_xor(a4, 32); a5 += __shfl_xor(a5, 32);
        a6 += __shfl_xor(a6, 32); a7 += __shfl_xor(a7, 32);
        if (half == 0) {
            uint4 r;
            r.x = (unsigned int)f2bf(a0) | ((unsigned int)f2bf(a1) << 16);
            r.y = (unsigned int)f2bf(a2) | ((unsigned int)f2bf(a3) << 16);
            r.z = (unsigned int)f2bf(a4) | ((unsigned int)f2bf(a5) << 16);
            r.w = (unsigned int)f2bf(a6) | ((unsigned int)f2bf(a7) << 16);
            *reinterpret_cast<uint4*>(&A[l][sub << 3]) = r;
        }
    }
    __syncthreads();

    // ---- P2: GEMM 16x256 ----
    const int lr = lane & 15;
    const int lg = lane >> 4;

    bf16x8 afr[8];
#pragma unroll
    for (int ks = 0; ks < 8; ++ks)
        afr[ks] = *reinterpret_cast<const bf16x8*>(&A[lr][ks * 32 + lg * 8]);

#pragma unroll
    for (int c = 0; c < 4; ++c) {
        const int ct = (wave << 2) + c;
        f32x4 acc = {0.f, 0.f, 0.f, 0.f};
        const unsigned short* bp = Wt + (size_t)(ct * 16 + lr) * D + lg * 8;
#pragma unroll
        for (int ks = 0; ks < 8; ++ks) {
            bf16x8 bfr = *reinterpret_cast<const bf16x8*>(bp + ks * 32);
            acc = __builtin_amdgcn_mfma_f32_16x16x32_bf16(afr[ks], bfr, acc, 0, 0, 0);
        }
        const float bv = bias[ct * 16 + lr];
#pragma unroll
        for (int jj = 0; jj < 4; ++jj) {
            int row = node0 + lg * 4 + jj;
            if (row < N) {
                float v = acc[jj] + bv;
                out[(size_t)row * D + ct * 16 + lr] = v > 0.f ? v : 0.f;
            }
        }
    }
}

// ---------------------------------------------------------------------------
// Fallback kernels (ws too small): direct atomic scatter + VALU linear.
// ---------------------------------------------------------------------------
__global__ __launch_bounds__(256) void scatter_kernel(
    const float* __restrict__ feature, const int* __restrict__ src,
    const int* __restrict__ dst, float* __restrict__ agg, int E)
{
    int edge = blockIdx.x * (blockDim.x >> 6) + (threadIdx.x >> 6);
    int lane = threadIdx.x & 63;
    if (edge >= E) return;
    int s = src[edge];
    int d = dst[edge];
    const float4 v = *reinterpret_cast<const float4*>(feature + (size_t)s * D + lane * 4);
    float* o = agg + (size_t)d * D + lane * 4;
    atomicAdd(o + 0, v.x);
    atomicAdd(o + 1, v.y);
    atomicAdd(o + 2, v.z);
    atomicAdd(o + 3, v.w);
}

#define BM 32
__global__ __launch_bounds__(256) void linear_relu_kernel(
    float* __restrict__ h, const float* __restrict__ W,
    const float* __restrict__ b, int n_nodes)
{
    __shared__ float sA[BM][D];
    const int node0 = blockIdx.x * BM;
    const int t = threadIdx.x;
    for (int m = 0; m < BM; ++m) {
        int nd = node0 + m;
        sA[m][t] = (nd < n_nodes) ? h[(size_t)nd * D + t] : 0.0f;
    }
    __syncthreads();
    float acc[BM];
#pragma unroll
    for (int m = 0; m < BM; ++m) acc[m] = 0.0f;
    for (int kk = 0; kk < D; ++kk) {
        float w = W[kk * D + t];
#pragma unroll
        for (int m = 0; m < BM; ++m) acc[m] += sA[m][kk] * w;
    }
    const float bias = b[t];
    for (int m = 0; m < BM; ++m) {
        int nd = node0 + m;
        if (nd < n_nodes) {
            float v = acc[m] + bias;
            h[(size_t)nd * D + t] = v > 0.0f ? v : 0.0f;
        }
    }
}

// ---------------------------------------------------------------------------
extern "C" void kernel_launch(void* const* d_in, const int* in_sizes, int n_in,
                              void* d_out, int out_size, void* d_ws, size_t ws_size,
                              hipStream_t stream)
{
    const float* feature = (const float*)d_in[0];
    const int*   src     = (const int*)d_in[1];
    const int*   dst     = (const int*)d_in[2];
    const float* W       = (const float*)d_in[3];
    const float* b       = (const float*)d_in[4];
    float*       out     = (float*)d_out;

    const int E = in_sizes[1];
    const int N = in_sizes[0] / D;
    const int K  = (N + GSIZE - 1) >> GSHIFT;   // 16-node groups
    const int NC = (N + CBIN - 1) >> CSHIFT;    // coarse bins
    const int chunk = (E + NB_P - 1) / NB_P;

    // ---- workspace layout -------------------------------------------------
    size_t off = 0;
    auto alloc = [&](size_t bytes, size_t align) {
        off = (off + align - 1) / align * align;
        size_t r = off; off += bytes; return r;
    };
    size_t o_gcntC = alloc((size_t)NC * 4, 16);
    size_t o_csrA  = alloc((size_t)NC * CAPC * 4, 16);
    size_t o_gcnt  = alloc((size_t)K * 4, 16);
    size_t o_csrB  = alloc((size_t)K * CAPG2 * 4, 16);
    size_t o_wt    = alloc((size_t)D * D * 2, 16);
    size_t o_fbf   = alloc((size_t)N * D * 2, 16);
    size_t need_full = off;

    char* ws = (char*)d_ws;

    // capacity guards: mean + 8*sigma + 16 must fit each region
    // (group: 512 + 181 + 16 = 709 <= 1024; bin: 8184 + 724 + 16 = 8924 <= 9216)
    const double mg = (double)E / K;
    const double mc = (double)E / NC;
    const bool cap_ok =
        (mg + 8.0 * __builtin_sqrt(mg) + 16.0 <= (double)CAPG2) &&
        (mc + 8.0 * __builtin_sqrt(mc) + 16.0 <= (double)CAPC) &&
        (NC <= NCMAX);

    if (ws_size >= need_full && cap_ok) {
        int* gcntC = (int*)(ws + o_gcntC);
        int* csrA  = (int*)(ws + o_csrA);
        int* gcnt  = (int*)(ws + o_gcnt);
        int* csrB  = (int*)(ws + o_csrB);
        unsigned short* Wt  = (unsigned short*)(ws + o_wt);
        unsigned short* fbf = (unsigned short*)(ws + o_fbf);

        const long n8 = (long)N * D / 8;
        const int nConvF = (int)((n8 + 255) / 256);
        const int nConvW = (D * D / 4 + 255) / 256;

        hipMemsetAsync(gcntC, 0, (size_t)NC * 4, stream);

        part_kernel<<<NB_P + nConvF + nConvW, 256, 0, stream>>>(
            src, dst, gcntC, csrA, feature, fbf, n8, W, Wt,
            E, NC, chunk, nConvF);

        regroup_kernel<<<NC, 256, 0, stream>>>(csrA, gcntC, csrB, gcnt, K);

        agg_gemm_kernel<<<(N + TN - 1) / TN, 256, 0, stream>>>(
            fbf, csrB, gcnt, Wt, b, out, N);
    } else {
        hipMemsetAsync(d_out, 0, (size_t)out_size * sizeof(float), stream);
        scatter_kernel<<<(E + 3) / 4, 256, 0, stream>>>(feature, src, dst, out, E);
        linear_relu_kernel<<<(N + BM - 1) / BM, 256, 0, stream>>>(out, W, b, N);
    }
}